// Round 3
// baseline (430.039 us; speedup 1.0000x reference)
//
#include <hip/hip_runtime.h>
#include <hip/hip_bf16.h>
#include <stdint.h>

#define TREES 8192
#define HID   256
#define CH    16
#define KL    4
#define G     4            // trees per block
#define LDSS  264          // LDS row stride in bf16 elems (256 + 8 pad)

typedef short bf16x8 __attribute__((ext_vector_type(8)));
typedef float f32x4  __attribute__((ext_vector_type(4)));

__device__ __forceinline__ unsigned short f2bf(float f) {
    unsigned u = __builtin_bit_cast(unsigned, f);
    u += 0x7FFFu + ((u >> 16) & 1u);
    return (unsigned short)(u >> 16);
}
__device__ __forceinline__ float elu1(float x) {
    return x > 0.f ? x : (__expf(x) - 1.f);
}

// Prologue: convert fp32 weights to bf16, transposed [k][h][d] -> [k][d][h],
// and precompute bz_sum[d] = sum_k bz[k][d] in fp32.
// Thread tid <-> (k, h, d) with d fastest => coalesced fp32 reads,
// scattered bf16 writes (write-side amplification ~4 us, acceptable).
__global__ void prep_kernel(const float* __restrict__ Wz,
                            const float* __restrict__ bz,
                            const float* __restrict__ Wzf,
                            unsigned short* __restrict__ WzT,
                            unsigned short* __restrict__ WzfT,
                            float* __restrict__ bzsum) {
    int tid = blockIdx.x * blockDim.x + threadIdx.x;
    if (tid < KL * HID * HID) {
        int k = tid >> 16;
        int h = (tid >> 8) & 255;
        int d = tid & 255;
        WzT[(k << 16) + (d << 8) + h] = f2bf(Wz[tid]);
    } else if (tid < KL * HID * HID + HID * HID) {
        int i = tid - KL * HID * HID;
        int h = i >> 8, d = i & 255;
        WzfT[(d << 8) + h] = f2bf(Wzf[i]);
    } else if (tid < KL * HID * HID + HID * HID + HID) {
        int d = tid - (KL * HID * HID + HID * HID);
        float s = 0.f;
        #pragma unroll
        for (int k = 0; k < KL; ++k) s += bz[k * HID + d];
        bzsum[d] = s;
    }
}

__global__ __launch_bounds__(256) void ptree_kernel(
    const float* __restrict__ x,               // [N,256] fp32
    const int* __restrict__ leaf,              // [T,16]
    const float* __restrict__ bzf,             // [256] fp32
    const unsigned short* __restrict__ WzT,    // [K][d][h] bf16 (ws)
    const unsigned short* __restrict__ WzfT,   // [d][h] bf16 (ws)
    const float* __restrict__ bzsum,           // [256] f32 (ws)
    float* __restrict__ out,                   // [T,256] fp32
    int nrows)
{
    __shared__ __align__(16) unsigned short sh[G][CH][LDSS];
    const int tid  = threadIdx.x;
    const int lane = tid & 63;
    const int wave = tid >> 6;
    const int t0   = blockIdx.x * G;
    const int ncol = lane & 15;   // MFMA: A-row m / B-col n / C col
    const int quad = lane >> 4;   // MFMA: k-group; C row group

    // ---- Gather x rows for G trees into LDS as bf16.
    // chunk = 8 floats: two float4 loads (32B contiguous per lane) -> uint4 write.
    #pragma unroll
    for (int i = 0; i < (G * CH * 32) / 256; ++i) {   // 8 iters
        int cid = i * 256 + tid;
        int g   = cid >> 9;
        int row = (cid >> 5) & 15;
        int ch  = cid & 31;
        int idx = leaf[(t0 + g) * CH + row];
        idx = (idx >= 0 && idx < nrows) ? idx : 0;    // defensive clamp
        const float* src = x + (size_t)idx * HID + ch * 8;
        float4 v0 = *(const float4*)src;
        float4 v1 = *(const float4*)(src + 4);
        union { uint4 u4; unsigned short s[8]; } U;
        U.s[0] = f2bf(v0.x); U.s[1] = f2bf(v0.y);
        U.s[2] = f2bf(v0.z); U.s[3] = f2bf(v0.w);
        U.s[4] = f2bf(v1.x); U.s[5] = f2bf(v1.y);
        U.s[6] = f2bf(v1.z); U.s[7] = f2bf(v1.w);
        *(uint4*)&sh[g][row][ch * 8] = U.u4;
    }

    float bzs[4];
    #pragma unroll
    for (int nt = 0; nt < 4; ++nt) bzs[nt] = bzsum[wave * 64 + nt * 16 + ncol];
    const float bzf_v = bzf[wave * 64 + lane];

    __syncthreads();

    // ---- GEMM1: rolled_sum[c][d] = sum_k data[(c-k)&15][:] @ Wz[k][:][d]
    f32x4 acc1[G][4];
    #pragma unroll
    for (int g = 0; g < G; ++g)
        #pragma unroll
        for (int nt = 0; nt < 4; ++nt) acc1[g][nt] = f32x4{0.f, 0.f, 0.f, 0.f};

    const unsigned short* wz_base = WzT + (wave * 64 + ncol) * HID + quad * 8;
    #pragma unroll
    for (int k = 0; k < KL; ++k) {
        const int arow = (ncol - k) & 15;   // rolled child row for A-lane m=ncol
        #pragma unroll
        for (int kt = 0; kt < 8; ++kt) {
            bf16x8 b[4];
            #pragma unroll
            for (int nt = 0; nt < 4; ++nt)
                b[nt] = *(const bf16x8*)(wz_base + k * 65536 + nt * 16 * HID + kt * 32);
            #pragma unroll
            for (int g = 0; g < G; ++g) {
                bf16x8 a = *(const bf16x8*)&sh[g][arow][kt * 32 + quad * 8];
                #pragma unroll
                for (int nt = 0; nt < 4; ++nt)
                    acc1[g][nt] = __builtin_amdgcn_mfma_f32_16x16x32_bf16(a, b[nt], acc1[g][nt], 0, 0, 0);
            }
        }
    }

    __syncthreads();   // all GEMM1 LDS reads done before h overwrites tiles

    // ---- Epilogue 1: +bz_sum, ELU, write h (bf16) back into the same tiles.
    #pragma unroll
    for (int g = 0; g < G; ++g)
        #pragma unroll
        for (int nt = 0; nt < 4; ++nt)
            #pragma unroll
            for (int r = 0; r < 4; ++r) {
                float v = acc1[g][nt][r] + bzs[nt];
                sh[g][quad * 4 + r][wave * 64 + nt * 16 + ncol] = f2bf(elu1(v));
            }

    __syncthreads();

    // ---- GEMM2: h @ Wzf
    f32x4 acc2[G][4];
    #pragma unroll
    for (int g = 0; g < G; ++g)
        #pragma unroll
        for (int nt = 0; nt < 4; ++nt) acc2[g][nt] = f32x4{0.f, 0.f, 0.f, 0.f};

    const unsigned short* wzf_base = WzfT + (wave * 64 + ncol) * HID + quad * 8;
    #pragma unroll
    for (int kt = 0; kt < 8; ++kt) {
        bf16x8 b[4];
        #pragma unroll
        for (int nt = 0; nt < 4; ++nt)
            b[nt] = *(const bf16x8*)(wzf_base + nt * 16 * HID + kt * 32);
        #pragma unroll
        for (int g = 0; g < G; ++g) {
            bf16x8 a = *(const bf16x8*)&sh[g][ncol][kt * 32 + quad * 8];
            #pragma unroll
            for (int nt = 0; nt < 4; ++nt)
                acc2[g][nt] = __builtin_amdgcn_mfma_f32_16x16x32_bf16(a, b[nt], acc2[g][nt], 0, 0, 0);
        }
    }

    // ---- Epilogue 2: child-sum (4 in-lane rows + cross-quad shfl), +16*bzf,
    //      ELU, coalesced fp32 store.
    #pragma unroll
    for (int g = 0; g < G; ++g) {
        float s[4];
        #pragma unroll
        for (int nt = 0; nt < 4; ++nt) {
            s[nt] = acc2[g][nt][0] + acc2[g][nt][1] + acc2[g][nt][2] + acc2[g][nt][3];
            s[nt] += __shfl_xor(s[nt], 16);
            s[nt] += __shfl_xor(s[nt], 32);
        }
        float r = quad == 0 ? s[0] : quad == 1 ? s[1] : quad == 2 ? s[2] : s[3];
        r += 16.f * bzf_v;
        r = elu1(r);
        out[(t0 + g) * HID + wave * 64 + lane] = r;
    }
}

extern "C" void kernel_launch(void* const* d_in, const int* in_sizes, int n_in,
                              void* d_out, int out_size, void* d_ws, size_t ws_size,
                              hipStream_t stream) {
    (void)out_size; (void)ws_size;
    // Resolve inputs by their unique flat element counts (order-proof).
    const void* p_x = nullptr; const void* p_Wz = nullptr; const void* p_bz = nullptr;
    const void* p_Wzf = nullptr; const void* p_bzf = nullptr; const void* p_leaf = nullptr;
    for (int i = 0; i < n_in; ++i) {
        switch (in_sizes[i]) {
            case 200000 * 256:   p_x    = d_in[i]; break;
            case KL * 256 * 256: p_Wz   = d_in[i]; break;
            case KL * 256:       p_bz   = d_in[i]; break;
            case 256 * 256:      p_Wzf  = d_in[i]; break;
            case 256:            p_bzf  = d_in[i]; break;
            case TREES * CH:     p_leaf = d_in[i]; break;
        }
    }
    const float* x    = (const float*)p_x;
    const float* Wz   = (const float*)p_Wz;
    const float* bz   = (const float*)p_bz;
    const float* Wzf  = (const float*)p_Wzf;
    const float* bzf  = (const float*)p_bzf;
    const int*   leaf = (const int*)p_leaf;

    unsigned short* WzT  = (unsigned short*)d_ws;        // 512 KB
    unsigned short* WzfT = WzT + KL * HID * HID;         // 128 KB
    float*          bzsum = (float*)(WzfT + HID * HID);  // 1 KB

    const int prep_threads = KL * HID * HID + HID * HID + HID;
    prep_kernel<<<(prep_threads + 255) / 256, 256, 0, stream>>>(Wz, bz, Wzf, WzT, WzfT, bzsum);
    ptree_kernel<<<TREES / G, 256, 0, stream>>>(x, leaf, bzf, WzT, WzfT, bzsum,
                                                (float*)d_out, 200000);
}

// Round 4
// 349.536 us; speedup vs baseline: 1.2303x; 1.2303x over previous
//
#include <hip/hip_runtime.h>
#include <hip/hip_bf16.h>
#include <stdint.h>

#define TREES 8192
#define HID   256
#define CH    16
#define KL    4
#define G     8            // trees per block
#define LDSS  264          // LDS row stride in bf16 elems (256 + 8 pad)

typedef short bf16x8 __attribute__((ext_vector_type(8)));
typedef float f32x4  __attribute__((ext_vector_type(4)));

__device__ __forceinline__ unsigned short f2bf(float f) {
    unsigned u = __builtin_bit_cast(unsigned, f);
    u += 0x7FFFu + ((u >> 16) & 1u);
    return (unsigned short)(u >> 16);
}
__device__ __forceinline__ float elu1(float x) {
    return x > 0.f ? x : (__expf(x) - 1.f);
}

// ---- Prep A: tiled transpose fp32 [h][d] -> bf16 [d][h], coalesced both sides.
// grid (4,4,5): z = 0..3 -> Wz layer k, z = 4 -> Wzf. 64x64 tiles, 256 threads.
__global__ void prep_transpose(const float* __restrict__ Wz,
                               const float* __restrict__ Wzf,
                               unsigned short* __restrict__ WzT,
                               unsigned short* __restrict__ WzfT) {
    __shared__ unsigned short ts[64][65];
    const int k  = blockIdx.z;
    const int h0 = blockIdx.x * 64;
    const int d0 = blockIdx.y * 64;
    const float* src = (k < KL) ? (Wz + (k << 16)) : Wzf;
    unsigned short* dst = (k < KL) ? (WzT + (k << 16)) : WzfT;
    const int tid = threadIdx.x;
    const int jc  = tid & 63;
    #pragma unroll
    for (int r = 0; r < 16; ++r) {
        int i = r * 4 + (tid >> 6);
        ts[jc][i] = f2bf(src[(h0 + i) * HID + d0 + jc]);   // coalesced read
    }
    __syncthreads();
    #pragma unroll
    for (int r = 0; r < 16; ++r) {
        int jl = r * 4 + (tid >> 6);
        dst[(d0 + jl) * HID + h0 + jc] = ts[jl][jc];       // coalesced write
    }
}

// ---- Prep B: bz_sum[d] = sum_k bz[k][d] (fp32).
__global__ void prep_bzsum(const float* __restrict__ bz, float* __restrict__ bzsum) {
    int d = threadIdx.x;
    float s = 0.f;
    #pragma unroll
    for (int k = 0; k < KL; ++k) s += bz[k * HID + d];
    bzsum[d] = s;
}

__global__ __launch_bounds__(256, 2) void ptree_kernel(
    const float* __restrict__ x,               // [N,256] fp32
    const int* __restrict__ leaf,              // [T,16]
    const float* __restrict__ bzf,             // [256] fp32
    const unsigned short* __restrict__ WzT,    // [K][d][h] bf16 (ws)
    const unsigned short* __restrict__ WzfT,   // [d][h] bf16 (ws)
    const float* __restrict__ bzsum,           // [256] f32 (ws)
    float* __restrict__ out,                   // [T,256] fp32
    int nrows)
{
    __shared__ __align__(16) unsigned short sh[G][CH][LDSS];  // gathered leaves
    __shared__ __align__(16) unsigned short hs[CH][LDSS];     // hsum, rows 8..15 unused
    const int tid  = threadIdx.x;
    const int lane = tid & 63;
    const int wave = tid >> 6;
    const int t0   = blockIdx.x * G;
    const int ncol = lane & 15;
    const int quad = lane >> 4;

    // ---- Gather x rows for G trees into LDS as bf16 (2x float4 -> 16B write).
    #pragma unroll
    for (int i = 0; i < (G * CH * 32) / 256; ++i) {   // 16 iters
        int cid = i * 256 + tid;
        int g   = cid >> 9;
        int row = (cid >> 5) & 15;
        int ch  = cid & 31;
        int idx = leaf[(t0 + g) * CH + row];
        idx = (idx >= 0 && idx < nrows) ? idx : 0;
        const float* src = x + (size_t)idx * HID + ch * 8;
        float4 v0 = *(const float4*)src;
        float4 v1 = *(const float4*)(src + 4);
        union { uint4 u4; unsigned short s[8]; } U;
        U.s[0] = f2bf(v0.x); U.s[1] = f2bf(v0.y);
        U.s[2] = f2bf(v0.z); U.s[3] = f2bf(v0.w);
        U.s[4] = f2bf(v1.x); U.s[5] = f2bf(v1.y);
        U.s[6] = f2bf(v1.z); U.s[7] = f2bf(v1.w);
        *(uint4*)&sh[g][row][ch * 8] = U.u4;
    }

    float bzs[4], bzfv[4];
    #pragma unroll
    for (int nt = 0; nt < 4; ++nt) {
        bzs[nt]  = bzsum[wave * 64 + nt * 16 + ncol];
        bzfv[nt] = bzf[wave * 64 + nt * 16 + ncol];
    }

    __syncthreads();

    // ---- GEMM1: rolled_sum[c][d] = sum_k data[(c-k)&15][:] @ Wz[k][:][d]
    //      B-frags prefetched 1 step ahead (32 MFMAs between issue and use).
    f32x4 acc1[G][4];
    #pragma unroll
    for (int g = 0; g < G; ++g)
        #pragma unroll
        for (int nt = 0; nt < 4; ++nt) acc1[g][nt] = f32x4{0.f, 0.f, 0.f, 0.f};

    const unsigned short* wz_base = WzT + (wave * 64 + ncol) * HID + quad * 8;
    bf16x8 bc[4], bn[4];
    #pragma unroll
    for (int nt = 0; nt < 4; ++nt)
        bc[nt] = *(const bf16x8*)(wz_base + nt * 16 * HID);

    #pragma unroll 2
    for (int s = 0; s < KL * 8; ++s) {
        const int sn = (s < KL * 8 - 1) ? s + 1 : s;
        const unsigned short* pn = wz_base + (sn >> 3) * 65536 + (sn & 7) * 32;
        #pragma unroll
        for (int nt = 0; nt < 4; ++nt)
            bn[nt] = *(const bf16x8*)(pn + nt * 16 * HID);
        const int k    = s >> 3;
        const int kt   = s & 7;
        const int arow = (ncol - k) & 15;
        #pragma unroll
        for (int g = 0; g < G; ++g) {
            bf16x8 a = *(const bf16x8*)&sh[g][arow][kt * 32 + quad * 8];
            #pragma unroll
            for (int nt = 0; nt < 4; ++nt)
                acc1[g][nt] = __builtin_amdgcn_mfma_f32_16x16x32_bf16(a, bc[nt], acc1[g][nt], 0, 0, 0);
        }
        #pragma unroll
        for (int nt = 0; nt < 4; ++nt) bc[nt] = bn[nt];
    }

    // ---- hsum: +bz, ELU per (child,d), sum over 16 children in-register.
    //      C-layout: col=ncol (d), row=quad*4+r (child). xor-shfl sums quads.
    #pragma unroll
    for (int g = 0; g < G; ++g)
        #pragma unroll
        for (int nt = 0; nt < 4; ++nt) {
            float s = 0.f;
            #pragma unroll
            for (int r = 0; r < 4; ++r) s += elu1(acc1[g][nt][r] + bzs[nt]);
            s += __shfl_xor(s, 16);
            s += __shfl_xor(s, 32);
            if (quad == 0) hs[g][wave * 64 + nt * 16 + ncol] = f2bf(s);
        }

    __syncthreads();

    // ---- GEMM2 (tiny): out[t][d] = elu(hsum[t][:] @ Wzf[:][d] + 16*bzf[d])
    //      A rows = trees (8 used of 16). 8 kt-steps x 4 nt = 32 MFMAs/wave.
    f32x4 acc2[4];
    #pragma unroll
    for (int nt = 0; nt < 4; ++nt) acc2[nt] = f32x4{0.f, 0.f, 0.f, 0.f};

    const unsigned short* wzf_base = WzfT + (wave * 64 + ncol) * HID + quad * 8;
    #pragma unroll 2
    for (int kt = 0; kt < 8; ++kt) {
        bf16x8 a = *(const bf16x8*)&hs[ncol & 7][kt * 32 + quad * 8];
        if (ncol >= 8) a = bf16x8{0, 0, 0, 0, 0, 0, 0, 0};
        #pragma unroll
        for (int nt = 0; nt < 4; ++nt) {
            bf16x8 b = *(const bf16x8*)(wzf_base + nt * 16 * HID + kt * 32);
            acc2[nt] = __builtin_amdgcn_mfma_f32_16x16x32_bf16(a, b, acc2[nt], 0, 0, 0);
        }
    }

    // ---- Store: row=quad*4+r is the tree (0..7 valid), col=d.
    #pragma unroll
    for (int nt = 0; nt < 4; ++nt)
        #pragma unroll
        for (int r = 0; r < 4; ++r) {
            int tree = quad * 4 + r;
            if (tree < G) {
                float v = elu1(acc2[nt][r] + 16.f * bzfv[nt]);
                out[(size_t)(t0 + tree) * HID + wave * 64 + nt * 16 + ncol] = v;
            }
        }
}

extern "C" void kernel_launch(void* const* d_in, const int* in_sizes, int n_in,
                              void* d_out, int out_size, void* d_ws, size_t ws_size,
                              hipStream_t stream) {
    (void)out_size; (void)ws_size;
    const void* p_x = nullptr; const void* p_Wz = nullptr; const void* p_bz = nullptr;
    const void* p_Wzf = nullptr; const void* p_bzf = nullptr; const void* p_leaf = nullptr;
    for (int i = 0; i < n_in; ++i) {
        switch (in_sizes[i]) {
            case 200000 * 256:   p_x    = d_in[i]; break;
            case KL * 256 * 256: p_Wz   = d_in[i]; break;
            case KL * 256:       p_bz   = d_in[i]; break;
            case 256 * 256:      p_Wzf  = d_in[i]; break;
            case 256:            p_bzf  = d_in[i]; break;
            case TREES * CH:     p_leaf = d_in[i]; break;
        }
    }
    const float* x    = (const float*)p_x;
    const float* Wz   = (const float*)p_Wz;
    const float* bz   = (const float*)p_bz;
    const float* Wzf  = (const float*)p_Wzf;
    const float* bzf  = (const float*)p_bzf;
    const int*   leaf = (const int*)p_leaf;

    unsigned short* WzT  = (unsigned short*)d_ws;        // 512 KB
    unsigned short* WzfT = WzT + KL * HID * HID;         // 128 KB
    float*          bzsum = (float*)(WzfT + HID * HID);  // 1 KB

    dim3 tg(4, 4, KL + 1);
    prep_transpose<<<tg, 256, 0, stream>>>(Wz, Wzf, WzT, WzfT);
    prep_bzsum<<<1, HID, 0, stream>>>(bz, bzsum);
    ptree_kernel<<<TREES / G, 256, 0, stream>>>(x, leaf, bzf, WzT, WzfT, bzsum,
                                                (float*)d_out, 200000);
}